// Round 5
// baseline (151.835 us; speedup 1.0000x reference)
//
#include <hip/hip_runtime.h>

// SoftMinLayer: sliding-window squared distance + softmin pooling.
// x: (512,1024) f32, sh: (100,50) f32 -> out (512,100) f32.
//
// R5: single fused kernel, wave = (i,k), lane = 16-j tile.
// Key fix vs R4 (VGPR=24 proved the 17x4x16 FIR nest never unrolled ->
// runtime predicates per FMA): load x window into registers FIRST
// (17 ds_read_b128, constant indices), then a clean 50x16 fully-unrolled
// FMA nest -- 800 v_fmac with SGPR shapelet operand, zero conditionals.
//  - shapelet wave-uniform -> SGPRs (readfirstlane'd row pointer)
//  - lds_x AND lds_sq both stored swizzled (phys = F + (F>>2)):
//    per-lane b128 reads walk 20 words/lane -> conflict-free
//  - sq_win computed by waves 6-9 from global while waves 0-3 stage x
//  - ssq cancels exactly in Dm = D - min D -> dropped
//  - exact softmin: lane min(16) -> shfl_xor wave min -> 16 exp2 -> wave sums

#define N_SEQ   512
#define Q_LEN   1024
#define K_SH    100
#define L_SH    50
#define J_WIN   974
// exp(ALPHA*Dm), Dm=(g-gm)/L, g = L*D unscaled: exp2(C2E*(g-gm)),
// C2E = ALPHA*log2(e)/L = -100 * 1.4426950408889634 / 50
#define C2E     (-2.8853900817779268f)

#define LX_F4   336   // swizzled x: logical F4 0..268 -> phys F+(F>>2) <= 335
#define SQ_F4   320   // swizzled sq: logical F4 0..255 -> phys <= 318

__global__ __launch_bounds__(640, 4)
void softmin_fused(const float* __restrict__ x, const float* __restrict__ sh,
                   float* __restrict__ out) {
    __shared__ __align__(16) float lds_x [LX_F4 * 4];   // 5376 B
    __shared__ __align__(16) float lds_sq[SQ_F4 * 4];   // 5120 B

    const int i    = blockIdx.x;
    const int tid  = threadIdx.x;
    const int lane = tid & 63;
    const int wave = tid >> 6;                 // 0..9
    const int k    = blockIdx.y * 10 + wave;   // 0..99 (grid.y = 10)

    const float4* gx = (const float4*)(x + (size_t)i * Q_LEN);

    // ---- waves 0-3: stage x row swizzled ----
    if (tid < 256) {
        ((float4*)lds_x)[tid + (tid >> 2)] = gx[tid];
    }

    // ---- waves 6-9: sq_win[4t..4t+3] from global, swizzled; pad with 0 ----
    {
        const int t = tid - 384;
        if (t >= 0 && t < 256) {
            float4 r = make_float4(0.f, 0.f, 0.f, 0.f);
            if (t < 244) {
                float s0 = 0.f, s1 = 0.f, s2 = 0.f, s3 = 0.f;
                #pragma unroll
                for (int q = 0; q < 14; ++q) {
                    float4 v = (t + q < 256) ? gx[t + q]
                                             : make_float4(0.f, 0.f, 0.f, 0.f);
                    const float xc[4] = {v.x, v.y, v.z, v.w};
                    #pragma unroll
                    for (int c = 0; c < 4; ++c) {
                        const int p = 4 * q + c;
                        const float x2 = xc[c] * xc[c];
                        if (p >= 0 && p <= 49) s0 += x2;
                        if (p >= 1 && p <= 50) s1 += x2;
                        if (p >= 2 && p <= 51) s2 += x2;
                        if (p >= 3 && p <= 52) s3 += x2;
                    }
                }
                r = make_float4(s0, s1, s2, s3);
            }
            ((float4*)lds_sq)[t + (t >> 2)] = r;
        }
    }

    // ---- shapelet row -> SGPRs (wave-uniform address) ----
    const int kw = __builtin_amdgcn_readfirstlane(k);
    const float* __restrict__ srow = sh + (size_t)kw * L_SH;
    float s[L_SH];
    #pragma unroll
    for (int l = 0; l < L_SH; ++l) s[l] = srow[l];

    __syncthreads();

    // ---- load lane's x window into registers (constant LDS offsets) ----
    // lane covers j in [16*lane, 16*lane+16); needs x[16*lane .. 16*lane+67].
    // logical F4 = 4*lane + q (q=0..16) -> phys = 5*lane + q + (q>>2)
    float xw[68];
    {
        const char* xbase = (const char*)lds_x + 80 * lane;
        #pragma unroll
        for (int q = 0; q < 17; ++q) {
            const float4 v = *(const float4*)(xbase + 16 * (q + (q >> 2)));
            xw[4 * q + 0] = v.x;
            xw[4 * q + 1] = v.y;
            xw[4 * q + 2] = v.z;
            xw[4 * q + 3] = v.w;
        }
    }

    // ---- FIR: 800 FMAs, all indices compile-time ----
    float acc[16];
    #pragma unroll
    for (int d = 0; d < 16; ++d) acc[d] = 0.f;
    #pragma unroll
    for (int l = 0; l < L_SH; ++l) {
        const float sv = s[l];
        #pragma unroll
        for (int d = 0; d < 16; ++d)
            acc[d] = fmaf(xw[l + d], sv, acc[d]);
    }

    // ---- g[d] = sq_win[j] - 2*acc[d]  (unscaled; ssq cancels in Dm) ----
    float g[16];
    {
        const char* sqbase = (const char*)lds_sq + 80 * lane;  // F=4*lane+d4 -> phys 5*lane+d4
        #pragma unroll
        for (int d4 = 0; d4 < 4; ++d4) {
            const float4 sq = *(const float4*)(sqbase + 16 * d4);
            g[4 * d4 + 0] = fmaf(-2.f, acc[4 * d4 + 0], sq.x);
            g[4 * d4 + 1] = fmaf(-2.f, acc[4 * d4 + 1], sq.y);
            g[4 * d4 + 2] = fmaf(-2.f, acc[4 * d4 + 2], sq.z);
            g[4 * d4 + 3] = fmaf(-2.f, acc[4 * d4 + 3], sq.w);
        }
    }

    // ---- mask invalid j (also kills any garbage from unwritten LDS) ----
    const int j0 = 16 * lane;
    #pragma unroll
    for (int d = 0; d < 16; ++d)
        if (j0 + d >= J_WIN) g[d] = 3.0e38f;

    // ---- exact wave min ----
    float gm = g[0];
    #pragma unroll
    for (int d = 1; d < 16; ++d) gm = fminf(gm, g[d]);
    #pragma unroll
    for (int off = 1; off < 64; off <<= 1)
        gm = fminf(gm, __shfl_xor(gm, off, 64));

    // ---- softmin sums ----
    float S = 0.f, T = 0.f;
    #pragma unroll
    for (int d = 0; d < 16; ++d) {
        const float t = g[d] - gm;                       // >= 0; masked: huge -> w = 0
        const float w = __builtin_amdgcn_exp2f(C2E * t); // exp(ALPHA*t/L)
        S += w;
        T = fmaf(t, w, T);
    }
    #pragma unroll
    for (int off = 1; off < 64; off <<= 1) {
        S += __shfl_xor(S, off, 64);
        T += __shfl_xor(T, off, 64);
    }

    if (lane == 0)
        out[(size_t)i * K_SH + k] = (T / S) * (1.f / (float)L_SH);
}

extern "C" void kernel_launch(void* const* d_in, const int* in_sizes, int n_in,
                              void* d_out, int out_size, void* d_ws, size_t ws_size,
                              hipStream_t stream) {
    const float* x  = (const float*)d_in[0];   // (512, 1024) f32
    const float* sh = (const float*)d_in[1];   // (100, 50)  f32
    float* out = (float*)d_out;                // (512, 100) f32

    dim3 grid(N_SEQ, 10);
    softmin_fused<<<grid, 640, 0, stream>>>(x, sh, out);
}

// Round 6
// 148.879 us; speedup vs baseline: 1.0199x; 1.0199x over previous
//
#include <hip/hip_runtime.h>

// SoftMinLayer: sliding-window squared distance + softmin pooling.
// x: (512,1024) f32, sh: (100,50) f32 -> out (512,100) f32.
//
// R6: wave = (i,k), lane = 16-j tile, FIR transposed to p=l+d grouping.
// Diagnosis R1/R4/R5: local arrays >~128B (s_reg[50], xw[68]) defeat
// SROA/unroll -> dynamic indices -> 3x VALU (VGPR=24..32 was the tell).
// Fix: NO retained x window. For each of the 17 window float4s, apply it
// to every acc[d] it feeds (l = p-d) and drop it. Live set = acc[16] + one
// float4. Each step is an explicit template instantiation fir_step<Q> --
// there is no outer loop that can fail to unroll; guards fold at
// instantiation. Same 17 ds_read_b128 + 800 v_fmac per lane as the ring
// design, with ~28 VGPRs of pressure.
//  - shapelet wave-uniform -> SGPRs (readfirstlane'd row base)
//  - lds_x / lds_sq swizzled (phys F4 = F + (F>>2)): conflict-free b128
//  - ssq cancels exactly in Dm = D - min D -> dropped
//  - exact softmin: lane min(16) -> shfl_xor wave min -> 16 exp2 -> sums

#define N_SEQ   512
#define Q_LEN   1024
#define K_SH    100
#define L_SH    50
#define J_WIN   974
// exp(ALPHA*Dm), Dm=(g-gm)/L, g = L*D unscaled: exp2(C2E*(g-gm)),
// C2E = ALPHA*log2(e)/L = -100 * 1.4426950408889634 / 50
#define C2E     (-2.8853900817779268f)

#define LX_F4   336   // swizzled x: logical F4 0..268 -> phys F+(F>>2) <= 335
#define SQ_F4   320   // swizzled sq: logical F4 0..255 -> phys <= 318

// One window float4 (logical F4 = 4*lane + Q), applied to all acc[d] it
// feeds: component c is x offset p = 4Q+c; acc[d] needs l = p-d in [0,50).
// All indices template/unroll constants -> guards fold, FMAs take the
// SGPR shapelet operand directly.
template<int Q>
__device__ __forceinline__ void fir_step(const char* xbase,
                                         const float (&s)[L_SH],
                                         float (&acc)[16]) {
    const float4 xv = *(const float4*)(xbase + 16 * (Q + (Q >> 2)));
    const float xc[4] = {xv.x, xv.y, xv.z, xv.w};
    #pragma unroll
    for (int c = 0; c < 4; ++c) {
        #pragma unroll
        for (int d = 0; d < 16; ++d) {
            const int l = 4 * Q + c - d;
            if (l >= 0 && l < L_SH)
                acc[d] = fmaf(xc[c], s[l], acc[d]);
        }
    }
}

__global__ __launch_bounds__(640, 2)
void softmin_fused(const float* __restrict__ x, const float* __restrict__ sh,
                   float* __restrict__ out) {
    __shared__ __align__(16) float lds_x [LX_F4 * 4];   // 5376 B
    __shared__ __align__(16) float lds_sq[SQ_F4 * 4];   // 5120 B

    const int i    = blockIdx.x;
    const int tid  = threadIdx.x;
    const int lane = tid & 63;
    const int wave = tid >> 6;                 // 0..9
    const int k    = blockIdx.y * 10 + wave;   // 0..99 (grid.y = 10)

    const float4* gx = (const float4*)(x + (size_t)i * Q_LEN);

    // ---- waves 0-3: stage x row swizzled ----
    if (tid < 256) {
        ((float4*)lds_x)[tid + (tid >> 2)] = gx[tid];
    }

    // ---- waves 6-9: sq_win[4t..4t+3] from global, swizzled; pad with 0 ----
    {
        const int t = tid - 384;
        if (t >= 0 && t < 256) {
            float4 r = make_float4(0.f, 0.f, 0.f, 0.f);
            if (t < 244) {
                float s0 = 0.f, s1 = 0.f, s2 = 0.f, s3 = 0.f;
                #pragma unroll
                for (int q = 0; q < 14; ++q) {
                    float4 v = (t + q < 256) ? gx[t + q]
                                             : make_float4(0.f, 0.f, 0.f, 0.f);
                    const float xc[4] = {v.x, v.y, v.z, v.w};
                    #pragma unroll
                    for (int c = 0; c < 4; ++c) {
                        const int p = 4 * q + c;
                        const float x2 = xc[c] * xc[c];
                        if (p >= 0 && p <= 49) s0 += x2;
                        if (p >= 1 && p <= 50) s1 += x2;
                        if (p >= 2 && p <= 51) s2 += x2;
                        if (p >= 3 && p <= 52) s3 += x2;
                    }
                }
                r = make_float4(s0, s1, s2, s3);
            }
            ((float4*)lds_sq)[t + (t >> 2)] = r;
        }
    }

    // ---- shapelet row -> SGPRs (wave-uniform address) ----
    const int kw = __builtin_amdgcn_readfirstlane(k);
    const float* __restrict__ srow = sh + (size_t)kw * L_SH;
    float s[L_SH];
    #pragma unroll
    for (int l = 0; l < L_SH; ++l) s[l] = srow[l];

    __syncthreads();

    // ---- FIR: lane covers j in [16*lane, 16*lane+16) ----
    // window float4s: logical F4 = 4*lane + Q, Q = 0..16
    // phys byte = 16*(5*lane + Q + (Q>>2)) = 80*lane + 16*(Q + (Q>>2))
    float acc[16];
    #pragma unroll
    for (int d = 0; d < 16; ++d) acc[d] = 0.f;

    const char* xbase = (const char*)lds_x + 80 * lane;
    fir_step< 0>(xbase, s, acc);
    fir_step< 1>(xbase, s, acc);
    fir_step< 2>(xbase, s, acc);
    fir_step< 3>(xbase, s, acc);
    fir_step< 4>(xbase, s, acc);
    fir_step< 5>(xbase, s, acc);
    fir_step< 6>(xbase, s, acc);
    fir_step< 7>(xbase, s, acc);
    fir_step< 8>(xbase, s, acc);
    fir_step< 9>(xbase, s, acc);
    fir_step<10>(xbase, s, acc);
    fir_step<11>(xbase, s, acc);
    fir_step<12>(xbase, s, acc);
    fir_step<13>(xbase, s, acc);
    fir_step<14>(xbase, s, acc);
    fir_step<15>(xbase, s, acc);
    fir_step<16>(xbase, s, acc);

    // ---- g[d] = sq_win[j] - 2*acc[d]  (unscaled; ssq cancels in Dm) ----
    float g[16];
    {
        const char* sqbase = (const char*)lds_sq + 80 * lane; // F=4*lane+d4 -> phys 5*lane+d4
        #pragma unroll
        for (int d4 = 0; d4 < 4; ++d4) {
            const float4 sq = *(const float4*)(sqbase + 16 * d4);
            g[4 * d4 + 0] = fmaf(-2.f, acc[4 * d4 + 0], sq.x);
            g[4 * d4 + 1] = fmaf(-2.f, acc[4 * d4 + 1], sq.y);
            g[4 * d4 + 2] = fmaf(-2.f, acc[4 * d4 + 2], sq.z);
            g[4 * d4 + 3] = fmaf(-2.f, acc[4 * d4 + 3], sq.w);
        }
    }

    // ---- mask invalid j (also kills garbage from unwritten LDS pad) ----
    const int j0 = 16 * lane;
    #pragma unroll
    for (int d = 0; d < 16; ++d)
        if (j0 + d >= J_WIN) g[d] = 3.0e38f;

    // ---- exact wave min ----
    float gm = g[0];
    #pragma unroll
    for (int d = 1; d < 16; ++d) gm = fminf(gm, g[d]);
    #pragma unroll
    for (int off = 1; off < 64; off <<= 1)
        gm = fminf(gm, __shfl_xor(gm, off, 64));

    // ---- softmin sums ----
    float S = 0.f, T = 0.f;
    #pragma unroll
    for (int d = 0; d < 16; ++d) {
        const float t = g[d] - gm;                       // >= 0; masked -> w = 0
        const float w = __builtin_amdgcn_exp2f(C2E * t); // exp(ALPHA*t/L)
        S += w;
        T = fmaf(t, w, T);
    }
    #pragma unroll
    for (int off = 1; off < 64; off <<= 1) {
        S += __shfl_xor(S, off, 64);
        T += __shfl_xor(T, off, 64);
    }

    if (lane == 0)
        out[(size_t)i * K_SH + k] = (T / S) * (1.f / (float)L_SH);
}

extern "C" void kernel_launch(void* const* d_in, const int* in_sizes, int n_in,
                              void* d_out, int out_size, void* d_ws, size_t ws_size,
                              hipStream_t stream) {
    const float* x  = (const float*)d_in[0];   // (512, 1024) f32
    const float* sh = (const float*)d_in[1];   // (100, 50)  f32
    float* out = (float*)d_out;                // (512, 100) f32

    dim3 grid(N_SEQ, 10);
    softmin_fused<<<grid, 640, 0, stream>>>(x, sh, out);
}

// Round 7
// 147.288 us; speedup vs baseline: 1.0309x; 1.0108x over previous
//
#include <hip/hip_runtime.h>

// SoftMinLayer: sliding-window squared distance + softmin pooling.
// x: (512,1024) f32, sh: (100,50) f32 -> out (512,100) f32.
//
// R7: wave = (i,k), lane = 16-j tile. Same structure as R6 but the FIR
// inner product is INLINE ASM: v_fmac_f32 acc, s_shape, v_x with "s"
// constraint on the shapelet operand. R5/R6 identical counters (VGPR=32,
// dur ~110us, VALU ~2.4x the FMA floor) point to the compiler emitting
// v_mov s->v per FMA instead of folding the SGPR into v_fmac. The asm
// pins: SGPR operand folded, acc[] in registers, exactly 800 v_fmac.
//  - shapelet values pinned to SGPRs via readfirstlane (no uniformity
//    analysis needed)
//  - software-pipelined ds_read_b128: load float4 Q+1 before computing Q;
//    sq_win loaded before the FIR so latency hides under it
//  - lds_x / lds_sq swizzled (phys F4 = F + (F>>2)): conflict-free b128
//  - ssq cancels exactly in Dm = D - min D -> dropped
//  - exact softmin: lane min(16) -> shfl_xor wave min -> 16 exp2 -> sums

#define N_SEQ   512
#define Q_LEN   1024
#define K_SH    100
#define L_SH    50
#define J_WIN   974
// exp(ALPHA*Dm), Dm=(g-gm)/L, g = L*D unscaled: exp2(C2E*(g-gm)),
// C2E = ALPHA*log2(e)/L = -100 * 1.4426950408889634 / 50
#define C2E     (-2.8853900817779268f)

#define LX_F4   336   // swizzled x: logical F4 0..268 -> phys F+(F>>2) <= 335
#define SQ_F4   320   // swizzled sq: logical F4 0..255 -> phys <= 318

// One window float4 (logical F4 = 4*lane + Q): component c is x offset
// p = 4Q+c; acc[d] needs l = p-d in [0,50). Loads float4 Q+1 first
// (pipelined), then 64 asm v_fmac with SGPR shapelet operand.
template<int Q>
__device__ __forceinline__ float4 fir_step(const char* xbase,
                                           const float (&s)[L_SH],
                                           float (&acc)[16],
                                           float4 cur) {
    float4 nxt = cur;
    if constexpr (Q < 16) {
        constexpr int QN = Q + 1;
        nxt = *(const float4*)(xbase + 16 * (QN + (QN >> 2)));
    }
    #pragma unroll
    for (int c = 0; c < 4; ++c) {
        const float xv = (c == 0) ? cur.x : (c == 1) ? cur.y
                       : (c == 2) ? cur.z : cur.w;
        #pragma unroll
        for (int d = 0; d < 16; ++d) {
            const int l = 4 * Q + c - d;          // folds at unroll
            if (l >= 0 && l < L_SH) {
                asm("v_fmac_f32 %0, %1, %2"
                    : "+v"(acc[d])
                    : "s"(s[l]), "v"(xv));
            }
        }
    }
    return nxt;
}

__global__ __launch_bounds__(640, 8)
void softmin_fused(const float* __restrict__ x, const float* __restrict__ sh,
                   float* __restrict__ out) {
    __shared__ __align__(16) float lds_x [LX_F4 * 4];   // 5376 B
    __shared__ __align__(16) float lds_sq[SQ_F4 * 4];   // 5120 B

    const int i    = blockIdx.x;
    const int tid  = threadIdx.x;
    const int lane = tid & 63;
    const int wave = tid >> 6;                 // 0..9
    const int k    = blockIdx.y * 10 + wave;   // 0..99 (grid.y = 10)

    const float4* gx = (const float4*)(x + (size_t)i * Q_LEN);

    // ---- waves 0-3: stage x row swizzled ----
    if (tid < 256) {
        ((float4*)lds_x)[tid + (tid >> 2)] = gx[tid];
    }

    // ---- waves 6-9: sq_win[4t..4t+3] from global, swizzled; pad with 0 ----
    {
        const int t = tid - 384;
        if (t >= 0 && t < 256) {
            float4 r = make_float4(0.f, 0.f, 0.f, 0.f);
            if (t < 244) {
                float s0 = 0.f, s1 = 0.f, s2 = 0.f, s3 = 0.f;
                #pragma unroll
                for (int q = 0; q < 14; ++q) {
                    float4 v = (t + q < 256) ? gx[t + q]
                                             : make_float4(0.f, 0.f, 0.f, 0.f);
                    const float xc[4] = {v.x, v.y, v.z, v.w};
                    #pragma unroll
                    for (int c = 0; c < 4; ++c) {
                        const int p = 4 * q + c;
                        const float x2 = xc[c] * xc[c];
                        if (p >= 0 && p <= 49) s0 += x2;
                        if (p >= 1 && p <= 50) s1 += x2;
                        if (p >= 2 && p <= 51) s2 += x2;
                        if (p >= 3 && p <= 52) s3 += x2;
                    }
                }
                r = make_float4(s0, s1, s2, s3);
            }
            ((float4*)lds_sq)[t + (t >> 2)] = r;
        }
    }

    // ---- shapelet row -> SGPRs, pinned via readfirstlane ----
    const int kw = __builtin_amdgcn_readfirstlane(k);
    const float* __restrict__ srow = sh + (size_t)kw * L_SH;
    float s[L_SH];
    #pragma unroll
    for (int l = 0; l < L_SH; ++l)
        s[l] = __int_as_float(__builtin_amdgcn_readfirstlane(__float_as_int(srow[l])));

    __syncthreads();

    // ---- prefetch sq_win (latency hides under the FIR) ----
    const char* sqbase = (const char*)lds_sq + 80 * lane;  // F=4*lane+d4 -> phys 5*lane+d4
    const float4 sq0 = *(const float4*)(sqbase +  0);
    const float4 sq1 = *(const float4*)(sqbase + 16);
    const float4 sq2 = *(const float4*)(sqbase + 32);
    const float4 sq3 = *(const float4*)(sqbase + 48);

    // ---- FIR: lane covers j in [16*lane, 16*lane+16) ----
    // window float4s: logical F4 = 4*lane + Q, Q = 0..16
    // phys byte = 80*lane + 16*(Q + (Q>>2)); software-pipelined loads.
    float acc[16];
    #pragma unroll
    for (int d = 0; d < 16; ++d) acc[d] = 0.f;

    const char* xbase = (const char*)lds_x + 80 * lane;
    float4 cur = *(const float4*)(xbase + 0);
    cur = fir_step< 0>(xbase, s, acc, cur);
    cur = fir_step< 1>(xbase, s, acc, cur);
    cur = fir_step< 2>(xbase, s, acc, cur);
    cur = fir_step< 3>(xbase, s, acc, cur);
    cur = fir_step< 4>(xbase, s, acc, cur);
    cur = fir_step< 5>(xbase, s, acc, cur);
    cur = fir_step< 6>(xbase, s, acc, cur);
    cur = fir_step< 7>(xbase, s, acc, cur);
    cur = fir_step< 8>(xbase, s, acc, cur);
    cur = fir_step< 9>(xbase, s, acc, cur);
    cur = fir_step<10>(xbase, s, acc, cur);
    cur = fir_step<11>(xbase, s, acc, cur);
    cur = fir_step<12>(xbase, s, acc, cur);
    cur = fir_step<13>(xbase, s, acc, cur);
    cur = fir_step<14>(xbase, s, acc, cur);
    cur = fir_step<15>(xbase, s, acc, cur);
    (void)fir_step<16>(xbase, s, acc, cur);

    // ---- g[d] = sq_win[j] - 2*acc[d]  (unscaled; ssq cancels in Dm) ----
    float g[16];
    g[ 0] = fmaf(-2.f, acc[ 0], sq0.x);
    g[ 1] = fmaf(-2.f, acc[ 1], sq0.y);
    g[ 2] = fmaf(-2.f, acc[ 2], sq0.z);
    g[ 3] = fmaf(-2.f, acc[ 3], sq0.w);
    g[ 4] = fmaf(-2.f, acc[ 4], sq1.x);
    g[ 5] = fmaf(-2.f, acc[ 5], sq1.y);
    g[ 6] = fmaf(-2.f, acc[ 6], sq1.z);
    g[ 7] = fmaf(-2.f, acc[ 7], sq1.w);
    g[ 8] = fmaf(-2.f, acc[ 8], sq2.x);
    g[ 9] = fmaf(-2.f, acc[ 9], sq2.y);
    g[10] = fmaf(-2.f, acc[10], sq2.z);
    g[11] = fmaf(-2.f, acc[11], sq2.w);
    g[12] = fmaf(-2.f, acc[12], sq3.x);
    g[13] = fmaf(-2.f, acc[13], sq3.y);
    g[14] = fmaf(-2.f, acc[14], sq3.z);
    g[15] = fmaf(-2.f, acc[15], sq3.w);

    // ---- mask invalid j (also kills garbage from unwritten LDS pad) ----
    const int j0 = 16 * lane;
    #pragma unroll
    for (int d = 0; d < 16; ++d)
        if (j0 + d >= J_WIN) g[d] = 3.0e38f;

    // ---- exact wave min ----
    float gm = g[0];
    #pragma unroll
    for (int d = 1; d < 16; ++d) gm = fminf(gm, g[d]);
    #pragma unroll
    for (int off = 1; off < 64; off <<= 1)
        gm = fminf(gm, __shfl_xor(gm, off, 64));

    // ---- softmin sums ----
    float S = 0.f, T = 0.f;
    #pragma unroll
    for (int d = 0; d < 16; ++d) {
        const float t = g[d] - gm;                       // >= 0; masked -> w = 0
        const float w = __builtin_amdgcn_exp2f(C2E * t); // exp(ALPHA*t/L)
        S += w;
        T = fmaf(t, w, T);
    }
    #pragma unroll
    for (int off = 1; off < 64; off <<= 1) {
        S += __shfl_xor(S, off, 64);
        T += __shfl_xor(T, off, 64);
    }

    if (lane == 0)
        out[(size_t)i * K_SH + k] = (T / S) * (1.f / (float)L_SH);
}

extern "C" void kernel_launch(void* const* d_in, const int* in_sizes, int n_in,
                              void* d_out, int out_size, void* d_ws, size_t ws_size,
                              hipStream_t stream) {
    const float* x  = (const float*)d_in[0];   // (512, 1024) f32
    const float* sh = (const float*)d_in[1];   // (100, 50)  f32
    float* out = (float*)d_out;                // (512, 100) f32

    dim3 grid(N_SEQ, 10);
    softmin_fused<<<grid, 640, 0, stream>>>(x, sh, out);
}